// Round 7
// baseline (93.583 us; speedup 1.0000x reference)
//
#include <hip/hip_runtime.h>
#include <math.h>

#define BB 2
#define NN 256
#define EE 512
#define PP 256
#define DD 128
#define TT 8
#define KK 8
#define HDIM 256

// workspace offsets (floats)
#define WS_G      0          // B*E*K = 8192
#define WS_C0     8192       // 64
#define WS_V      8256       // B*N*HD = 131072
#define WS_EDGEF  139328     // B*E*D = 131072
#define WS_ETE    270400     // B*E*D = 131072
#define WS_HWT    401472     // B*N*E = 262144 (transposed Hw2)
#define WS_K2     663616     // 65536
#define WS_V2     729152     // 65536
// total 794688 floats = 3.18 MB

// prep grid roles
#define PB_GUM 16
#define PB_V   144    // 16 + 128 V-MLP blocks (512 rows, R=4)
#define PB_END 272    // + 128 kv blocks (512 pf rows, R=4)

__device__ inline unsigned rotl32(unsigned x, int d){ return (x<<d)|(x>>(32-d)); }

__device__ inline float bits_to_gumbel(unsigned bits){
  float f = __uint_as_float((bits>>9)|0x3f800000u) - 1.0f;
  const float minv = 1e-6f;
  const float maxv = 1.0f - 1e-6f;
  float u = f*(maxv-minv) + minv;
  u = fmaxf(minv, u);
  return -logf(-logf(u));
}

__device__ __forceinline__ void f4fma(float4& a, float x, const float4& w){
  a.x += x*w.x; a.y += x*w.y; a.z += x*w.z; a.w += x*w.w;
}

// ---- block-wide reduction of 4 values over 256 threads (4 waves) ----
__device__ __forceinline__ void block_reduce4_max(float v[4], float* wred){
  int lane = threadIdx.x & 63, wid = threadIdx.x >> 6;
  #pragma unroll
  for (int s=32;s>0;s>>=1){
    #pragma unroll
    for (int r=0;r<4;r++){ float o = __shfl_xor(v[r], s, 64); v[r] = fmaxf(v[r],o); }
  }
  if (lane==0){
    #pragma unroll
    for (int r=0;r<4;r++) wred[wid*4+r]=v[r];
  }
  __syncthreads();
  #pragma unroll
  for (int r=0;r<4;r++)
    v[r] = fmaxf(fmaxf(wred[0*4+r],wred[1*4+r]), fmaxf(wred[2*4+r],wred[3*4+r]));
  __syncthreads();
}

__device__ __forceinline__ void block_reduce4_sum(float v[4], float* wred){
  int lane = threadIdx.x & 63, wid = threadIdx.x >> 6;
  #pragma unroll
  for (int s=32;s>0;s>>=1){
    #pragma unroll
    for (int r=0;r<4;r++){ v[r] += __shfl_xor(v[r], s, 64); }
  }
  if (lane==0){
    #pragma unroll
    for (int r=0;r<4;r++) wred[wid*4+r]=v[r];
  }
  __syncthreads();
  #pragma unroll
  for (int r=0;r<4;r++)
    v[r] = (wred[0*4+r]+wred[1*4+r]) + (wred[2*4+r]+wred[3*4+r]);
  __syncthreads();
}

// ---- shared helper: 4 rows x (128->128) dense layer, float4 + 8-way k-split ----
__device__ __forceinline__ void mlp128_lds(const float (*in)[DD], const float* W, const float* bias,
                                           float (*outl)[DD], float* part, int t){
  int c=(t&31)*4, ks=t>>5;
  float4 a[4];
  #pragma unroll
  for (int r=0;r<4;r++) a[r]=make_float4(0.f,0.f,0.f,0.f);
  #pragma unroll 4
  for (int i=ks*16;i<ks*16+16;i++){
    float4 w = *(const float4*)&W[(size_t)i*DD+c];
    #pragma unroll
    for (int r=0;r<4;r++) f4fma(a[r], in[r][i], w);
  }
  #pragma unroll
  for (int r=0;r<4;r++) *(float4*)&part[(ks*4+r)*DD+c]=a[r];
  __syncthreads();
  int cc=t&127, rh=t>>7;
  for (int rr=rh; rr<4; rr+=2){
    float s=0.f;
    #pragma unroll
    for (int k2=0;k2<8;k2++) s+=part[(k2*4+rr)*DD+cc];
    outl[rr][cc]=s+bias[cc];
  }
  __syncthreads();
}

__device__ __forceinline__ void mlp128_glob(const float (*in)[DD], const float* W, const float* bias,
                                            float* dst, int r0, float* part, int t){
  int c=(t&31)*4, ks=t>>5;
  float4 a[4];
  #pragma unroll
  for (int r=0;r<4;r++) a[r]=make_float4(0.f,0.f,0.f,0.f);
  #pragma unroll 4
  for (int i=ks*16;i<ks*16+16;i++){
    float4 w = *(const float4*)&W[(size_t)i*DD+c];
    #pragma unroll
    for (int r=0;r<4;r++) f4fma(a[r], in[r][i], w);
  }
  #pragma unroll
  for (int r=0;r<4;r++) *(float4*)&part[(ks*4+r)*DD+c]=a[r];
  __syncthreads();
  int cc=t&127, rh=t>>7;
  for (int rr=rh; rr<4; rr+=2){
    float s=0.f;
    #pragma unroll
    for (int k2=0;k2<8;k2++) s+=part[(k2*4+rr)*DD+cc];
    dst[(size_t)(r0+rr)*DD+cc]=s+bias[cc];
  }
  __syncthreads();
}

// =========================================================================
// K1 prep: gumbel+c0 (0..15) | V-MLP (16..143) | k2/v2 chains (144..271)
// =========================================================================
__global__ void prep_kernel(float* g, float* c0, const float* w_b1,
                            const float* w_W2, const float* w_b2,
                            const float* af, const float* wW1, float* Vout,
                            const float* pf,
                            const float* kW, const float* kb, const float* ikW, const float* ikb,
                            const float* vW, const float* vb, const float* ivW, const float* ivb,
                            float* k2, float* v2){
  __shared__ float xs[4][DD];
  __shared__ float part[4*4*HDIM];   // 16KB (also 8*4*DD for kv helpers)
  __shared__ float wred[16];
  __shared__ float bufB[4][DD];
  int blk = blockIdx.x;
  int t = threadIdx.x;               // 256

  if (blk < PB_GUM){
    // ---- gumbel: j = blk*256 + t ----
    int j = blk*256 + t;
    {
      const unsigned k0=0u, k1=42u;
      const unsigned ks2 = k0^k1^0x1BD11BDAu;
      unsigned x0 = (unsigned)j, x1 = (unsigned)j + 4096u;
      const int r0_[4]={13,15,26,6}, r1_[4]={17,29,16,24};
      x0 += k0; x1 += k1;
      #pragma unroll
      for(int i=0;i<4;i++){ x0+=x1; x1=rotl32(x1,r0_[i]); x1^=x0; }
      x0+=k1; x1+=ks2+1u;
      #pragma unroll
      for(int i=0;i<4;i++){ x0+=x1; x1=rotl32(x1,r1_[i]); x1^=x0; }
      x0+=ks2; x1+=k0+2u;
      #pragma unroll
      for(int i=0;i<4;i++){ x0+=x1; x1=rotl32(x1,r0_[i]); x1^=x0; }
      x0+=k0; x1+=k1+3u;
      #pragma unroll
      for(int i=0;i<4;i++){ x0+=x1; x1=rotl32(x1,r1_[i]); x1^=x0; }
      x0+=k1; x1+=ks2+4u;
      #pragma unroll
      for(int i=0;i<4;i++){ x0+=x1; x1=rotl32(x1,r0_[i]); x1^=x0; }
      x0+=ks2; x1+=k0+5u;
      g[j]      = bits_to_gumbel(x0);
      g[j+4096] = bits_to_gumbel(x1);
    }
    if (blk == 0){
      float v4[4];
      v4[0] = fmaxf(w_b1[t],0.f)*w_W2[t]; v4[1]=0.f; v4[2]=0.f; v4[3]=0.f;
      block_reduce4_sum(v4, wred);
      if (t==0) c0[0] = v4[0] + w_b2[0];
    }
  } else if (blk < PB_V){
    // ---- V = af @ wW1[D:] (no bias), R=4 rows ----
    int r0 = (blk - PB_GUM)*4;
    const float* W = wW1 + (size_t)DD*HDIM;
    for (int i=t;i<4*DD;i+=256) xs[i>>7][i&127] = af[(size_t)(r0+(i>>7))*DD + (i&127)];
    __syncthreads();
    int c = (t&63)*4, ks = t>>6;
    float4 acc[4];
    #pragma unroll
    for (int r=0;r<4;r++) acc[r]=make_float4(0.f,0.f,0.f,0.f);
    #pragma unroll 8
    for (int i=ks*32; i<ks*32+32; i++){
      float4 w = *(const float4*)&W[(size_t)i*HDIM + c];
      #pragma unroll
      for (int r=0;r<4;r++) f4fma(acc[r], xs[r][i], w);
    }
    #pragma unroll
    for (int r=0;r<4;r++) *(float4*)&part[(ks*4+r)*HDIM + c] = acc[r];
    __syncthreads();
    #pragma unroll
    for (int r=0;r<4;r++){
      float s = (part[(0*4+r)*HDIM+t] + part[(1*4+r)*HDIM+t])
              + (part[(2*4+r)*HDIM+t] + part[(3*4+r)*HDIM+t]);
      Vout[(size_t)(r0+r)*HDIM + t] = s;
    }
  } else {
    // ---- k2/v2 chains from pf, R=4 rows ----
    int r0 = (blk - PB_V)*4;
    for (int i=t;i<4*DD;i+=256) xs[i>>7][i&127] = pf[(size_t)(r0+(i>>7))*DD + (i&127)];
    __syncthreads();
    mlp128_lds (xs, kW, kb, bufB, part, t);
    mlp128_glob(bufB, ikW, ikb, k2, r0, part, t);
    mlp128_lds (xs, vW, vb, bufB, part, t);
    mlp128_glob(bufB, ivW, ivb, v2, r0, part, t);
  }
}

// =========================================================================
// K2 edge: incidence + U1 MLP + relu-dot + masked softmax + aggregate
//          + type MLPs + gumbel softmax + ete + U2 + hw2 -> edgef, ete, HwT
// R=4 edges/block, 256 blocks. LDS overlaid (~50KB).
// =========================================================================
__global__ void edge_kernel(const float* Hm, const float* af, const float* at,
                            const float* Vm,
                            const float* wW1, const float* wb1, const float* wW2, const float* wb2,
                            const float* dW1, const float* db1, const float* dW2, const float* db2,
                            const float* fW1, const float* fb1, const float* fW2, const float* fb2,
                            const float* type_emb, const float* g, const float* c0p,
                            float* edgef_g, float* ete_g, float* HwT){
  __shared__ float bufA[4*4*HDIM];    // 16KB: split-k partials (U1/d/U2)
  __shared__ float bufB[4*4*HDIM];    // 16KB: [u|hwls|hcomp] phases<=6; partF phase 9
  __shared__ float w2s[HDIM*KK];      // 8KB: dW2
  __shared__ float w2l[HDIM];         // wW2
  __shared__ float et4[4][144];       // ef0/etype -> edgef/etype -> ete
  __shared__ float hd4[4][HDIM];      // relu-hidden -> U2
  __shared__ float redsm[256];
  __shared__ float wred[16];
  __shared__ float facs[4];
  __shared__ float zz[4][KK];
  __shared__ float pzs[4][KK];
  __shared__ float fdv[4][KK];
  __shared__ int   hcnt[4];
  float* u    = bufB;                 // [4][256]
  float* hwls = bufB + 1024;          // [4][256]
  int*   hcomp= (int*)(bufB + 2048);  // [4][256]

  int e0 = blockIdx.x*4;
  int b  = e0 >> 9;
  int t  = threadIdx.x;               // 256
  int lane = t & 63, wid = t >> 6;

  w2l[t] = wW2[t];
  for (int i=t;i<HDIM*KK;i+=256) w2s[i] = dW2[i];

  // phase 1: per-wave H compaction (wave wid owns edge wid); Hw shares H's pattern
  {
    int r = wid;
    const float* Hrow = Hm + (size_t)(e0+r)*NN;
    int base = 0;
    #pragma unroll
    for (int c4=0;c4<4;c4++){
      int n2 = c4*64 + lane;
      bool pred = (Hrow[n2] != 0.f);
      unsigned long long mask = __ballot(pred);
      int off = __popcll(mask & ((1ull<<lane)-1ull));
      if (pred) hcomp[r*256+base+off] = n2;
      base += __popcll(mask);
    }
    if (lane==0) hcnt[r] = base;
  }
  __syncthreads();
  // phase 2: incidence -> et4[r][0..127]=ef0, et4[r][128..135]=etype
  {
    int d = t & 127, eh = t >> 7;
    #pragma unroll
    for (int rr=0;rr<2;rr++){
      int r = eh*2 + rr;
      int tot = hcnt[r];
      float a = 0.f, a2 = 0.f;
      for (int i=0;i<tot;i++){
        int n2 = hcomp[r*256+i];
        a += af[((size_t)b*NN+n2)*DD + d];
        if (d < TT) a2 += at[((size_t)b*NN+n2)*TT + d];
      }
      et4[r][d] = a;
      if (d < TT) et4[r][DD+d] = a2;
    }
  }
  __syncthreads();
  // phase 3: U1 = ef0 @ wW1[:D] + wb1 -> u
  {
    int c=(t&63)*4, ks=t>>6;
    float4 acc[4];
    #pragma unroll
    for (int r=0;r<4;r++) acc[r]=make_float4(0.f,0.f,0.f,0.f);
    #pragma unroll 8
    for (int i=ks*32; i<ks*32+32; i++){
      float4 w = *(const float4*)&wW1[(size_t)i*HDIM + c];
      #pragma unroll
      for (int r=0;r<4;r++) f4fma(acc[r], et4[r][i], w);
    }
    #pragma unroll
    for (int r=0;r<4;r++) *(float4*)&bufA[(ks*4+r)*HDIM + c] = acc[r];
  }
  __syncthreads();
  {
    float bv = wb1[t];
    #pragma unroll
    for (int r=0;r<4;r++){
      float s = (bufA[(0*4+r)*HDIM+t] + bufA[(1*4+r)*HDIM+t])
              + (bufA[(2*4+r)*HDIM+t] + bufA[(3*4+r)*HDIM+t]);
      u[r*HDIM + t] = s + bv;
    }
  }
  __syncthreads();
  // phase 4: relu-dot + masked softmax -> hwls
  {
    int n = t;
    const float4* Vrow = (const float4*)(Vm + ((size_t)(b*NN)+n)*HDIM);
    float acc[4]={0.f,0.f,0.f,0.f};
    #pragma unroll 4
    for (int ii=0;ii<HDIM/4;ii++){
      float4 v = Vrow[ii];
      float w0=w2l[4*ii+0], w1=w2l[4*ii+1], wc=w2l[4*ii+2], w3=w2l[4*ii+3];
      #pragma unroll
      for (int r=0;r<4;r++){
        acc[r] += fmaxf(u[r*HDIM+4*ii+0]+v.x,0.f)*w0
                + fmaxf(u[r*HDIM+4*ii+1]+v.y,0.f)*w1
                + fmaxf(u[r*HDIM+4*ii+2]+v.z,0.f)*wc
                + fmaxf(u[r*HDIM+4*ii+3]+v.w,0.f)*w3;
      }
    }
    float b2v = wb2[0];
    float x[4], hv[4];
    #pragma unroll
    for (int r=0;r<4;r++){
      hv[r] = Hm[(size_t)(e0+r)*NN + n];
      x[r] = (hv[r]!=0.f) ? (acc[r]+b2v) : 0.f;
    }
    float m4[4]={x[0],x[1],x[2],x[3]};
    block_reduce4_max(m4, wred);
    float p4[4];
    #pragma unroll
    for (int r=0;r<4;r++) p4[r]=expf(x[r]-m4[r]);
    float s4[4]={p4[0],p4[1],p4[2],p4[3]};
    block_reduce4_sum(s4, wred);
    #pragma unroll
    for (int r=0;r<4;r++)
      hwls[r*NN+n] = (hv[r]!=0.f) ? p4[r]/s4[r] : 0.f;
  }
  __syncthreads();
  // phase 6: aggregate (reuse hcomp) -> et4[r][0..127]=edgef + global
  {
    int d = t & 127, eh = t >> 7;
    float eg[2];
    #pragma unroll
    for (int rr=0;rr<2;rr++){
      int r = eh*2 + rr;
      int tot = hcnt[r];
      float a = 0.f;
      for (int i=0;i<tot;i++){
        int n2 = hcomp[r*256+i];
        a += hwls[r*NN+n2]*af[((size_t)b*NN+n2)*DD + d];
      }
      eg[rr] = a;
    }
    #pragma unroll
    for (int rr=0;rr<2;rr++){
      int r = eh*2 + rr;
      et4[r][d] = eg[rr];
      edgef_g[(size_t)(e0+r)*DD + d] = eg[rr];
    }
  }
  __syncthreads();   // hcomp/hwls dead; bufB free for partF
  // phase 9: merged d/f MLPs
  {
    int c=(t&63)*4, ks=t>>6;
    float4 ad4[4], af4[4];
    #pragma unroll
    for (int r=0;r<4;r++){ ad4[r]=make_float4(0.f,0.f,0.f,0.f); af4[r]=make_float4(0.f,0.f,0.f,0.f); }
    #pragma unroll 4
    for (int i=ks*34;i<ks*34+34;i++){
      float4 wd = *(const float4*)&dW1[(size_t)i*HDIM+c];
      float4 wf = *(const float4*)&fW1[(size_t)i*HDIM+c];
      #pragma unroll
      for (int r=0;r<4;r++){ float x=et4[r][i]; f4fma(ad4[r],x,wd); f4fma(af4[r],x,wf); }
    }
    #pragma unroll
    for (int r=0;r<4;r++){
      *(float4*)&bufA[(ks*4+r)*HDIM+c]=ad4[r];
      *(float4*)&bufB[(ks*4+r)*HDIM+c]=af4[r];
    }
  }
  __syncthreads();
  {
    float bd = db1[t];
    float bf = fb1[t], fw = fW2[t];
    float v4[4];
    #pragma unroll
    for (int r=0;r<4;r++){
      float sd = (bufA[(0*4+r)*HDIM+t]+bufA[(1*4+r)*HDIM+t])
               + (bufA[(2*4+r)*HDIM+t]+bufA[(3*4+r)*HDIM+t]);
      hd4[r][t] = fmaxf(sd+bd, 0.f);
      float sf = (bufB[(0*4+r)*HDIM+t]+bufB[(1*4+r)*HDIM+t])
               + (bufB[(2*4+r)*HDIM+t]+bufB[(3*4+r)*HDIM+t]);
      v4[r] = fmaxf(sf+bf,0.f)*fw;
    }
    block_reduce4_sum(v4, wred);
    if (t<4) facs[t] = 1.f/(1.f+expf(-(v4[t]+fb2[0])));
  }
  // phase 10: logits (interleaved h -> 2-way banks), gumbel-softmax
  {
    int rr_ = t>>6, kk_ = (t>>3)&7, jj_ = t&7;
    float lp = 0.f;
    #pragma unroll 4
    for (int i=0;i<32;i++){
      int h = jj_ + 8*i;
      lp += hd4[rr_][h]*w2s[h*KK + kk_];
    }
    redsm[t] = lp;
  }
  __syncthreads();
  if (t < 32){
    int r = t>>3, k = t&7;
    float s = db2[k] + g[(size_t)(e0+r)*KK + k];
    #pragma unroll
    for (int j=0;j<8;j++) s += redsm[(r<<6)|(k<<3)|j];
    zz[r][k] = s*2.0f;               // /tau, tau=0.5
  }
  __syncthreads();
  if (t < 32){
    int r = t>>3, k = t&7;
    float m = zz[r][0];
    #pragma unroll
    for (int k2=1;k2<KK;k2++) m = fmaxf(m, zz[r][k2]);
    pzs[r][k] = expf(zz[r][k]-m);
  }
  __syncthreads();
  if (t < 32){
    int r = t>>3, k = t&7;
    float s = 0.f;
    #pragma unroll
    for (int k2=0;k2<KK;k2++) s += pzs[r][k2];
    fdv[r][k] = facs[r]*pzs[r][k]/s;
  }
  __syncthreads();
  // phase 11: ete -> et4[r][0..127] + global
  {
    int d = t&127;
    #pragma unroll
    for (int rr=0;rr<2;rr++){
      int r = 2*rr + (t>>7);
      float a = 0.f;
      #pragma unroll
      for (int k=0;k<KK;k++) a += fdv[r][k]*type_emb[(size_t)k*DD + d];
      et4[r][d] = a;
      ete_g[(size_t)(e0+r)*DD + d] = a;
    }
  }
  __syncthreads();
  // phase 12: U2 = ete @ wW1[:D] + wb1 -> hd4
  {
    int c=(t&63)*4, ks=t>>6;
    float4 a[4];
    #pragma unroll
    for (int r=0;r<4;r++) a[r]=make_float4(0.f,0.f,0.f,0.f);
    #pragma unroll 8
    for (int i=ks*32;i<ks*32+32;i++){
      float4 w = *(const float4*)&wW1[(size_t)i*HDIM+c];
      #pragma unroll
      for (int r=0;r<4;r++) f4fma(a[r], et4[r][i], w);
    }
    #pragma unroll
    for (int r=0;r<4;r++) *(float4*)&bufA[(ks*4+r)*HDIM+c]=a[r];
  }
  __syncthreads();
  {
    float bv = wb1[t];
    #pragma unroll
    for (int r=0;r<4;r++){
      float s = (bufA[(0*4+r)*HDIM+t]+bufA[(1*4+r)*HDIM+t])
              + (bufA[(2*4+r)*HDIM+t]+bufA[(3*4+r)*HDIM+t]);
      hd4[r][t] = s + bv;            // U2
    }
  }
  __syncthreads();
  // phase 13: hw2 relu-dot + leaky + full softmax -> HwT (transposed)
  {
    int n = t;
    const float4* Vrow = (const float4*)(Vm + ((size_t)(b*NN)+n)*HDIM);
    float acc[4]={0.f,0.f,0.f,0.f};
    #pragma unroll 4
    for (int ii=0;ii<HDIM/4;ii++){
      float4 v = Vrow[ii];
      float w0=w2l[4*ii+0], w1=w2l[4*ii+1], wc=w2l[4*ii+2], w3=w2l[4*ii+3];
      #pragma unroll
      for (int r=0;r<4;r++){
        acc[r] += fmaxf(hd4[r][4*ii+0]+v.x,0.f)*w0
                + fmaxf(hd4[r][4*ii+1]+v.y,0.f)*w1
                + fmaxf(hd4[r][4*ii+2]+v.z,0.f)*wc
                + fmaxf(hd4[r][4*ii+3]+v.w,0.f)*w3;
      }
    }
    float b2v = wb2[0];
    float c0 = c0p[0];
    float x[4], hv[4];
    #pragma unroll
    for (int r=0;r<4;r++){
      hv[r] = Hm[(size_t)(e0+r)*NN + n];
      float raw = (hv[r]!=0.f) ? (acc[r]+b2v) : c0;
      x[r] = raw>0.f ? raw : 0.01f*raw;
    }
    float m4[4]={x[0],x[1],x[2],x[3]};
    block_reduce4_max(m4, wred);
    float p4[4];
    #pragma unroll
    for (int r=0;r<4;r++) p4[r]=expf(x[r]-m4[r]);
    float s4[4]={p4[0],p4[1],p4[2],p4[3]};
    block_reduce4_sum(s4, wred);
    int eb = e0 & 511;
    float4 o4;
    o4.x = (hv[0]!=0.f)? p4[0]/s4[0] : 0.f;
    o4.y = (hv[1]!=0.f)? p4[1]/s4[1] : 0.f;
    o4.z = (hv[2]!=0.f)? p4[2]/s4[2] : 0.f;
    o4.w = (hv[3]!=0.f)? p4[3]/s4[3] : 0.f;
    *(float4*)(HwT + ((size_t)(b*NN)+n)*EE + eb) = o4;
  }
}

// =========================================================================
// K3 agent: msg (2 rows) + q2 + 4-head attention + out-proj + final MLP
// R=2 agent rows/block, 256 blocks. agf/q2 never leave LDS.
// =========================================================================
__global__ void agent_kernel(const float* HwT, const float* edgef, const float* ete,
                             const float* af,
                             const float* qW, const float* qb, const float* iqW, const float* iqb,
                             const float* k2, const float* v2,
                             const float* op_W, const float* op_b,
                             const float* oW1, const float* ob1,
                             const float* oW2, const float* ob2,
                             float* pnew, float* anew){
  __shared__ int   ecomp[EE];         // 2KB
  __shared__ float wcomp[EE];         // 2KB
  __shared__ int   wcnt[4];
  __shared__ float agfl[2][512];      // [agf(384) | pnew(128)]
  __shared__ float part[2048];        // 8KB
  __shared__ float Qs[2][DD];
  __shared__ float qr[2][DD];
  __shared__ float att[2][4][PP+1];
  __shared__ float o_l[2][DD];
  __shared__ float hid[2][HDIM];
  int n0 = blockIdx.x*2; int b = n0 >> 8; int t = threadIdx.x;
  int lane = t & 63, wid = t >> 6;

  // ---- msg for 2 rows (sequential; ecomp/wcomp reused) ----
  for (int rr=0;rr<2;rr++){
    int bn = n0 + rr;
    const float* wrow = HwT + (size_t)bn*EE;
    int total = 0;
    #pragma unroll
    for (int p=0;p<2;p++){
      int e = p*256 + t;
      float w = wrow[e];
      bool pred = (w != 0.f);
      unsigned long long mask = __ballot(pred);
      if (lane==0) wcnt[wid] = __popcll(mask);
      int off = __popcll(mask & ((1ull<<lane)-1ull));
      __syncthreads();
      int wb = total;
      for (int ww=0; ww<wid; ww++) wb += wcnt[ww];
      if (pred){ ecomp[wb+off] = e; wcomp[wb+off] = w; }
      total += wcnt[0]+wcnt[1]+wcnt[2]+wcnt[3];
      __syncthreads();
    }
    float acc = 0.f;
    const float* srcbase = (t < DD) ? (edgef + (size_t)b*EE*DD + t)
                                    : (ete   + (size_t)b*EE*DD + (t-DD));
    for (int i=0;i<total;i++){
      acc += wcomp[i] * srcbase[(size_t)ecomp[i]*DD];
    }
    agfl[rr][t] = acc;
    if (t < DD) agfl[rr][2*DD+t] = af[(size_t)bn*DD + t];
    __syncthreads();
  }
  // ---- q2 stage1: (2 x 384) @ (384 x 128), 8-way k-split ----
  int c=(t&31)*4, ps=t>>5;
  {
    float4 a[2];
    #pragma unroll
    for (int r=0;r<2;r++) a[r]=make_float4(0.f,0.f,0.f,0.f);
    #pragma unroll 4
    for (int i=ps*48;i<ps*48+48;i++){
      float4 w = *(const float4*)&qW[(size_t)i*DD+c];
      #pragma unroll
      for (int r=0;r<2;r++) f4fma(a[r], agfl[r][i], w);
    }
    #pragma unroll
    for (int r=0;r<2;r++) *(float4*)&part[(ps*2+r)*DD+c]=a[r];
  }
  __syncthreads();
  {
    int cc=t&127, r=t>>7;
    float s=0.f;
    #pragma unroll
    for (int k=0;k<8;k++) s+=part[(k*2+r)*DD+cc];
    Qs[r][cc]=s+qb[cc];
  }
  __syncthreads();
  // ---- q2 stage2: (2 x 128) @ (128 x 128) ----
  {
    float4 a[2];
    #pragma unroll
    for (int r=0;r<2;r++) a[r]=make_float4(0.f,0.f,0.f,0.f);
    #pragma unroll 4
    for (int i=ps*16;i<ps*16+16;i++){
      float4 w = *(const float4*)&iqW[(size_t)i*DD+c];
      #pragma unroll
      for (int r=0;r<2;r++) f4fma(a[r], Qs[r][i], w);
    }
    #pragma unroll
    for (int r=0;r<2;r++) *(float4*)&part[(ps*2+r)*DD+c]=a[r];
  }
  __syncthreads();
  {
    int cc=t&127, r=t>>7;
    float s=0.f;
    #pragma unroll
    for (int k=0;k<8;k++) s+=part[(k*2+r)*DD+cc];
    qr[r][cc]=s+iqb[cc];
  }
  __syncthreads();
  // ---- attention scores ----
  const float scale = 0.17677669529663687f;  // 1/sqrt(32)
  const float* krow = k2 + ((size_t)(b*PP) + t)*DD;
  #pragma unroll
  for (int h=0;h<4;h++){
    const float4* k4 = (const float4*)(krow + h*32);
    float s[2]={0.f,0.f};
    #pragma unroll
    for (int jj=0;jj<8;jj++){
      float4 kk = k4[jj];
      #pragma unroll
      for (int r=0;r<2;r++){
        s[r] += qr[r][h*32+jj*4+0]*kk.x + qr[r][h*32+jj*4+1]*kk.y
              + qr[r][h*32+jj*4+2]*kk.z + qr[r][h*32+jj*4+3]*kk.w;
      }
    }
    #pragma unroll
    for (int r=0;r<2;r++) att[r][h][t] = s[r]*scale;
  }
  __syncthreads();
  {
    for (int q = wid; q < 8; q += 4){
      int r = q >> 2, h = q & 3;
      float v0 = att[r][h][lane],     v1 = att[r][h][lane+64],
            ve = att[r][h][lane+128], v3 = att[r][h][lane+192];
      float m = fmaxf(fmaxf(v0,v1), fmaxf(ve,v3));
      #pragma unroll
      for (int s2=32;s2>0;s2>>=1) m = fmaxf(m, __shfl_xor(m, s2, 64));
      float e0 = expf(v0-m), e1 = expf(v1-m), e2 = expf(ve-m), e3 = expf(v3-m);
      float ss = (e0+e1)+(e2+e3);
      #pragma unroll
      for (int s2=32;s2>0;s2>>=1) ss += __shfl_xor(ss, s2, 64);
      float inv = 1.f/ss;
      att[r][h][lane] = e0*inv; att[r][h][lane+64] = e1*inv;
      att[r][h][lane+128] = e2*inv; att[r][h][lane+192] = e3*inv;
    }
  }
  __syncthreads();
  // ---- PV ----
  int h2 = c >> 5;
  {
    float4 acc[2];
    #pragma unroll
    for (int r=0;r<2;r++) acc[r]=make_float4(0.f,0.f,0.f,0.f);
    #pragma unroll 4
    for (int i=0;i<32;i++){
      int p = ps*32+i;
      float4 v = *(const float4*)&v2[((size_t)(b*PP)+p)*DD + c];
      #pragma unroll
      for (int r=0;r<2;r++) f4fma(acc[r], att[r][h2][p], v);
    }
    #pragma unroll
    for (int r=0;r<2;r++) *(float4*)&part[(ps*2+r)*DD+c]=acc[r];
  }
  __syncthreads();
  {
    int cc=t&127, r=t>>7;
    float s=0.f;
    #pragma unroll
    for (int k=0;k<8;k++) s+=part[(k*2+r)*DD+cc];
    o_l[r][cc]=s;
  }
  __syncthreads();
  // ---- out-proj -> pnew (+ LDS for final) ----
  {
    float4 a2[2];
    #pragma unroll
    for (int r=0;r<2;r++) a2[r]=make_float4(0.f,0.f,0.f,0.f);
    #pragma unroll 4
    for (int i=ps*16;i<ps*16+16;i++){
      float4 w = *(const float4*)&op_W[(size_t)i*DD + c];
      #pragma unroll
      for (int r=0;r<2;r++) f4fma(a2[r], o_l[r][i], w);
    }
    #pragma unroll
    for (int r=0;r<2;r++) *(float4*)&part[(ps*2+r)*DD+c]=a2[r];
  }
  __syncthreads();
  {
    int cc=t&127, r=t>>7;
    float s=0.f;
    #pragma unroll
    for (int k=0;k<8;k++) s+=part[(k*2+r)*DD+cc];
    float pv = s+op_b[cc];
    agfl[r][3*DD+cc] = pv;
    pnew[(size_t)(n0+r)*DD+cc] = pv;
  }
  __syncthreads();
  // ---- final stage1: (2 x 512) @ (512 x 256), KS=4, slice 128 ----
  {
    int c1=(t&63)*4, ks1=t>>6;
    float4 acc[2];
    #pragma unroll
    for (int r=0;r<2;r++) acc[r]=make_float4(0.f,0.f,0.f,0.f);
    #pragma unroll 8
    for (int i=ks1*128;i<ks1*128+128;i++){
      float4 w = *(const float4*)&oW1[(size_t)i*HDIM+c1];
      #pragma unroll
      for (int r=0;r<2;r++) f4fma(acc[r], agfl[r][i], w);
    }
    #pragma unroll
    for (int r=0;r<2;r++) *(float4*)&part[(ks1*2+r)*HDIM+c1]=acc[r];
  }
  __syncthreads();
  {
    float bv = ob1[t];
    #pragma unroll
    for (int r=0;r<2;r++){
      float s = (part[(0*2+r)*HDIM+t]+part[(1*2+r)*HDIM+t])
              + (part[(2*2+r)*HDIM+t]+part[(3*2+r)*HDIM+t]);
      hid[r][t] = fmaxf(s+bv, 0.f);
    }
  }
  __syncthreads();
  // ---- final stage2: (2 x 256) @ (256 x 128), KS=8, slice 32 ----
  {
    float4 a2[2];
    #pragma unroll
    for (int r=0;r<2;r++) a2[r]=make_float4(0.f,0.f,0.f,0.f);
    #pragma unroll 8
    for (int h=ps*32;h<ps*32+32;h++){
      float4 w = *(const float4*)&oW2[(size_t)h*DD+c];
      #pragma unroll
      for (int r=0;r<2;r++) f4fma(a2[r], hid[r][h], w);
    }
    #pragma unroll
    for (int r=0;r<2;r++) *(float4*)&part[(ps*2+r)*DD+c]=a2[r];
  }
  __syncthreads();
  {
    int cc=t&127, r=t>>7;
    float s=0.f;
    #pragma unroll
    for (int k=0;k<8;k++) s+=part[(k*2+r)*DD+cc];
    anew[(size_t)(n0+r)*DD+cc]=s+ob2[cc];
  }
}

extern "C" void kernel_launch(void* const* d_in, const int* in_sizes, int n_in,
                              void* d_out, int out_size, void* d_ws, size_t ws_size,
                              hipStream_t stream) {
  const float* af       = (const float*)d_in[0];
  const float* at       = (const float*)d_in[1];
  const float* pf       = (const float*)d_in[2];
  const float* Hm       = (const float*)d_in[3];
  const float* type_emb = (const float*)d_in[4];
  const float* w_W1 = (const float*)d_in[5];
  const float* w_b1 = (const float*)d_in[6];
  const float* w_W2 = (const float*)d_in[7];
  const float* w_b2 = (const float*)d_in[8];
  const float* d_W1 = (const float*)d_in[9];
  const float* d_b1 = (const float*)d_in[10];
  const float* d_W2 = (const float*)d_in[11];
  const float* d_b2 = (const float*)d_in[12];
  const float* f_W1 = (const float*)d_in[13];
  const float* f_b1 = (const float*)d_in[14];
  const float* f_W2 = (const float*)d_in[15];
  const float* f_b2 = (const float*)d_in[16];
  const float* o_W1 = (const float*)d_in[17];
  const float* o_b1 = (const float*)d_in[18];
  const float* o_W2 = (const float*)d_in[19];
  const float* o_b2 = (const float*)d_in[20];
  const float* q_W  = (const float*)d_in[21];
  const float* q_b  = (const float*)d_in[22];
  const float* k_W  = (const float*)d_in[23];
  const float* k_b  = (const float*)d_in[24];
  const float* v_W  = (const float*)d_in[25];
  const float* v_b  = (const float*)d_in[26];
  const float* iq_W = (const float*)d_in[27];
  const float* iq_b = (const float*)d_in[28];
  const float* ik_W = (const float*)d_in[29];
  const float* ik_b = (const float*)d_in[30];
  const float* iv_W = (const float*)d_in[31];
  const float* iv_b = (const float*)d_in[32];
  const float* op_W = (const float*)d_in[33];
  const float* op_b = (const float*)d_in[34];

  float* ws   = (float*)d_ws;
  float* out  = (float*)d_out;
  float* anew = out;                 // (B,N,D)
  float* pnew = out + BB*NN*DD;      // (B,N,D)

  prep_kernel<<<PB_END, 256, 0, stream>>>(
      ws+WS_G, ws+WS_C0, w_b1, w_W2, w_b2,
      af, w_W1, ws+WS_V,
      pf, k_W,k_b,ik_W,ik_b, v_W,v_b,iv_W,iv_b,
      ws+WS_K2, ws+WS_V2);
  edge_kernel<<<256,256,0,stream>>>(
      Hm, af, at, ws+WS_V,
      w_W1, w_b1, w_W2, w_b2,
      d_W1,d_b1,d_W2,d_b2, f_W1,f_b1,f_W2,f_b2,
      type_emb, ws+WS_G, ws+WS_C0,
      ws+WS_EDGEF, ws+WS_ETE, ws+WS_HWT);
  agent_kernel<<<256,256,0,stream>>>(
      ws+WS_HWT, ws+WS_EDGEF, ws+WS_ETE, af,
      q_W, q_b, iq_W, iq_b,
      ws+WS_K2, ws+WS_V2, op_W, op_b,
      o_W1,o_b1,o_W2,o_b2, pnew, anew);
}